// Round 2
// baseline (140.870 us; speedup 1.0000x reference)
//
#include <hip/hip_runtime.h>
#include <hip/hip_bf16.h>

// Problem: out[b,l,:] = code[b,l,:] @ W[l]   (B=256, L=64, C=256, HW=1024, fp32)
#define B_  256
#define L_  64
#define C_  256
#define HW_ 1024

typedef float  floatx4 __attribute__((ext_vector_type(4)));
typedef __bf16 bf16x8  __attribute__((ext_vector_type(8)));
typedef __bf16 bf16x4  __attribute__((ext_vector_type(4)));
typedef __bf16 bf16x2  __attribute__((ext_vector_type(2)));

#define LDT_A 72    // A row stride in bf16 (144 B): A write/read banks uniform (verified arithmetic)
#define LDB_ROW 128 // B row stride in BYTES (64 bf16, no pad; banks handled by XOR swizzle)

// Barrier that does NOT drain outstanding global loads (vmcnt): only LDS ops
// must be visible across the barrier; register prefetch stays in flight.
#define BARRIER_LDS() asm volatile("s_waitcnt lgkmcnt(0)\n\ts_barrier" ::: "memory")

// B LDS XOR swizzle (unchanged read path, verified): element (n,k) at byte
//   n*128 + ((c16 ^ g(n))*16) + (2k mod 16),  c16 = k/8,  g(n) = (n ^ (n>>2)) & 7
// Fragment reads: 8 lanes/chunk bank-uniform (free), 16B-aligned.
// Staging writes this round are b32 (bf16 k-pairs): bank = {(b_c4>>2)^g(n), b_c4&3};
// per wave-instr 16 n-quads x 4 k2 -> every bank hit by exactly 2 lanes = free (m136).
__device__ __forceinline__ int bswz(int n) { return (n ^ (n >> 2)) & 7; }

// RESTRUCTURE (round 2): tile 128x64 (was 128x128), 512 thr / 8 waves 2(m)x4(n),
// each wave 64x16 via 4x1 frags. Rationale: round-1 proved the A-load chain was
// NOT the critical path (depth-2 A = exactly neutral). Revised model: per-wave
// regs (32 AGPR acc + 64 VGPR pipeline) capped residency at 2 blocks/CU ->
// ~16 lockstepped waves/CU, Occupancy 30%, HBM stuck at 2.5 TB/s from too few
// independent load streams. Halving BN cuts acc to 16 AGPR, Breg to 16, Areg
// depth-1 -> ~70 regs/wave -> 6 waves/EU -> 3 blocks/CU (forced via
// __launch_bounds__(512,6)), grid 2048 -> +50% resident waves, 3 independent
// barrier domains/CU, smoother tail. W HBM traffic unchanged (same m-split).
__global__ __launch_bounds__(512, 6)
void gld_mfma_kernel(const float* __restrict__ code,
                     const float* __restrict__ W,
                     float* __restrict__ out)
{
    const int tid = threadIdx.x;

    // XCD swizzle: id = ll + 8*(m + 2n + 32*lh), l = 8*lh + ll. All 32 blocks
    // of one filter l share id%8 (-> same XCD if dispatch round-robins), so
    // W[l] slices and A[l] panels stay hot in one XCD L2.
    const int id  = blockIdx.x;
    const int ll  = id & 7;
    const int inr = id >> 3;                 // 0..255
    const int m0  = (inr & 1) * 128;         // batch rows
    const int n0  = ((inr >> 1) & 15) * 64;  // HW cols (16 slices of 64)
    const int l   = (inr >> 5) * 8 + ll;     // filter

    __shared__ __bf16 Alds[128 * LDT_A];              // A tile [m][k] bf16 (18 KB)
    __shared__ unsigned char Blds[64 * LDB_ROW];      // B tile [n][k] bf16, swizzled (8 KB)

    const int lane = tid & 63;
    const int wave = tid >> 6;          // 0..7
    const int wm = (wave >> 2) * 64;    // 0,64   (m offset of wave)
    const int wn = (wave & 3) * 16;     // 0,16,32,48 (n offset of wave)

    floatx4 acc[4];
    #pragma unroll
    for (int i = 0; i < 4; ++i)
        acc[i] = (floatx4)0.0f;

    // A staging: 128 rows x 64 k fp32 -> 4 float4 per thread (coalesced)
    const int a_row = tid >> 4;          // 0..31 (4 passes of 32 rows)
    const int a_kc  = (tid & 15) * 4;    // k-chunk
    // B staging: 64 n x 64 k fp32 -> 2 float4 per thread. Thread owns a
    // 4n x 2k micro-tile: float4 loads at 2 consecutive k-rows (4x256B runs/instr).
    const int b_i  = tid & 15;           // n-quad (n = 4*b_i + j, 0..63)
    const int b_c4 = tid >> 4;           // k-pair index 0..31 (k = 2*b_c4, +1)

    const float* aBase = code + (size_t)m0 * (L_ * C_) + (size_t)l * C_ + a_kc;
    const float* wBase = W + (size_t)l * (C_ * HW_) + (size_t)(2 * b_c4) * HW_ + n0 + 4 * b_i;

    floatx4 Areg[4];      // depth-1 (depth-2 measured neutral in round 1)
    floatx4 Breg[2][2];   // depth-2 ping-pong

    // ---- prologue: A(0), B(0), B(64) ----
    #pragma unroll
    for (int p = 0; p < 4; ++p)
        Areg[p] = *(const floatx4*)(aBase + (size_t)(p * 32 + a_row) * (L_ * C_));
    #pragma unroll
    for (int r = 0; r < 2; ++r)
        Breg[0][r] = *(const floatx4*)(wBase + (size_t)r * HW_);
    #pragma unroll
    for (int r = 0; r < 2; ++r)
        Breg[1][r] = *(const floatx4*)(wBase + (size_t)(64 + r) * HW_);

    // B LDS write addresses (loop-invariant): row 4*b_i+j, k-pair 2*b_c4
    // byte = row*128 + (((b_c4>>2) ^ g(row))<<4) + ((b_c4&3)<<2)
    int bwaddr[4];
    #pragma unroll
    for (int j = 0; j < 4; ++j) {
        const int row = 4 * b_i + j;
        bwaddr[j] = row * LDB_ROW + (((b_c4 >> 2) ^ bswz(row)) << 4) + ((b_c4 & 3) << 2);
    }

    #pragma unroll
    for (int kb = 0; kb < C_; kb += 64) {
        const int pp = (kb >> 6) & 1;

        // ---- stage B first: data is 2 iters old -> no vmcnt stall ----
        #pragma unroll
        for (int j = 0; j < 4; ++j) {
            bf16x2 h;
            h.x = (__bf16)Breg[pp][0][j];    // k = 2*b_c4
            h.y = (__bf16)Breg[pp][1][j];    // k = 2*b_c4 + 1
            *(bf16x2*)&Blds[bwaddr[j]] = h;
        }
        // ---- stage A: waits on A loads issued last iter ----
        #pragma unroll
        for (int p = 0; p < 4; ++p) {
            bf16x4 h;
            h.x = (__bf16)Areg[p].x; h.y = (__bf16)Areg[p].y;
            h.z = (__bf16)Areg[p].z; h.w = (__bf16)Areg[p].w;
            *(bf16x4*)&Alds[(p * 32 + a_row) * LDT_A + a_kc] = h;
        }

        // ---- issue prefetch: A for kb+64 (depth-1), B for kb+128 (depth-2) ----
        if (kb + 64 < C_) {
            #pragma unroll
            for (int p = 0; p < 4; ++p)
                Areg[p] = *(const floatx4*)(aBase + (size_t)(p * 32 + a_row) * (L_ * C_) + (kb + 64));
        }
        if (kb + 128 < C_) {
            #pragma unroll
            for (int r = 0; r < 2; ++r)
                Breg[pp][r] = *(const floatx4*)(wBase + (size_t)(kb + 128 + r) * HW_);
        }

        BARRIER_LDS();   // LDS writes visible; vmcnt NOT drained

        // ---- compute: 2 k-steps of 32, 8 MFMA per wave ----
        #pragma unroll
        for (int ks = 0; ks < 2; ++ks) {
            bf16x8 af[4], bfr;
            const int koff = ks * 32 + (lane >> 4) * 8;
            #pragma unroll
            for (int i = 0; i < 4; ++i)
                af[i] = *(const bf16x8*)&Alds[(wm + i * 16 + (lane & 15)) * LDT_A + koff];
            {
                const int n = wn + (lane & 15);
                bfr = *(const bf16x8*)&Blds[n * LDB_ROW + (((koff >> 3) ^ bswz(n)) << 4)];
            }
            #pragma unroll
            for (int i = 0; i < 4; ++i)
                acc[i] = __builtin_amdgcn_mfma_f32_16x16x32_bf16(af[i], bfr, acc[i], 0, 0, 0);
        }

        BARRIER_LDS();   // all waves done reading before next overwrite
    }

    // ---- epilogue: C/D layout col=lane&15, row=(lane>>4)*4+reg ----
    const int col0 = lane & 15;
    const int row0 = (lane >> 4) * 4;
    #pragma unroll
    for (int i = 0; i < 4; ++i) {
        const int m = m0 + wm + i * 16 + row0;
        const int n = n0 + wn + col0;
        float* o = out + (size_t)m * (L_ * HW_) + (size_t)l * HW_ + n;
        #pragma unroll
        for (int r = 0; r < 4; ++r)
            o[(size_t)r * (L_ * HW_)] = acc[i][r];
    }
}

extern "C" void kernel_launch(void* const* d_in, const int* in_sizes, int n_in,
                              void* d_out, int out_size, void* d_ws, size_t ws_size,
                              hipStream_t stream) {
    const float* code = (const float*)d_in[0];   // [256, 64, 256] fp32
    const float* W    = (const float*)d_in[1];   // [64, 256, 1024] fp32
    float* out        = (float*)d_out;           // [256, 64, 32, 32] fp32

    gld_mfma_kernel<<<dim3(2048), 512, 0, stream>>>(code, W, out);
}

// Round 3
// 139.545 us; speedup vs baseline: 1.0095x; 1.0095x over previous
//
#include <hip/hip_runtime.h>
#include <hip/hip_bf16.h>

// Problem: out[b,l,:] = code[b,l,:] @ W[l]   (B=256, L=64, C=256, HW=1024, fp32)
#define B_  256
#define L_  64
#define C_  256
#define HW_ 1024

typedef float  floatx4 __attribute__((ext_vector_type(4)));
typedef __bf16 bf16x8  __attribute__((ext_vector_type(8)));
typedef __bf16 bf16x4  __attribute__((ext_vector_type(4)));

// Barrier that does NOT drain outstanding global loads (vmcnt): only LDS ops
// must be visible across the barrier; register prefetch stays in flight.
#define BARRIER_LDS() asm volatile("s_waitcnt lgkmcnt(0)\n\ts_barrier" ::: "memory")

// Unified LDS layout for BOTH A and B tiles (each is [row][64 k] bf16, 128 B
// rows, XOR-swizzled -- the verified round-0 B scheme):
//   element (row,k) at byte  row*128 + (((k>>3) ^ g(row))<<4) + (2k mod 16)
//   g(row) = (row ^ (row>>2)) & 7
// Fragment reads (bf16x8 at chunk c = koff>>3, rows base+(lane&15)): within a
// 16-lane group g spans 8 values -> 2 lanes/chunk-column = conflict-free (m136).
__device__ __forceinline__ int bswz(int n) { return (n ^ (n >> 2)) & 7; }
__device__ __forceinline__ int lds_addr(int row, int c16, int off) {
    return row * 128 + ((c16 ^ bswz(row)) << 4) + off;
}

// ROUND 3 RESTRUCTURE: traffic-minimizing 256x256 tile.
// Evidence: r1 (load slack) null, r2 (occupancy +50%) NEGATIVE while its load
// traffic rose 1.5x and time rose 16% -> surviving model: kernel is paced by
// total global-load bytes, amplified by tiling:
//   loads = code*(HW/BN) + W*(B/BM)  MB
//   128x128: 268 MB (3.2x input);  256x256: 134 MB (1.6x input).
// BM=256 covers the whole batch (W read exactly once); BN=256 -> 4 n-slices.
// Grid 64l x 4n = 256 blocks = exactly 1/CU (32/XCD). 8 waves, each 128x64
// (8x4 frags of 16x16x32). LDS = A 32KB + B 32KB = 64 KB single-buffered,
// same 2-barrier reg-prefetch loop as round 0. Same-l blocks share an XCD
// (id%8=ll) so the A panel (256 KB) stays in that XCD's L2 across its 4 users.
__global__ __launch_bounds__(512, 2)
void gld_mfma_kernel(const float* __restrict__ code,
                     const float* __restrict__ W,
                     float* __restrict__ out)
{
    const int tid = threadIdx.x;

    // id = ll + 8*(n_idx + 4*lh), l = 8*lh + ll: same-l blocks share id%8.
    const int id   = blockIdx.x;
    const int ll   = id & 7;
    const int rest = id >> 3;               // 0..31
    const int n0   = (rest & 3) * 256;      // HW cols (4 slices of 256)
    const int l    = (rest >> 2) * 8 + ll;  // filter

    __shared__ unsigned char Alds[256 * 128];   // A tile [m][k] bf16, swizzled (32 KB)
    __shared__ unsigned char Blds[256 * 128];   // B tile [n][k] bf16, swizzled (32 KB)

    const int lane = tid & 63;
    const int wave = tid >> 6;          // 0..7
    const int wm = (wave >> 2) * 128;   // 0,128       (m offset of wave)
    const int wn = (wave & 3) * 64;     // 0,64,128,192 (n offset of wave)

    floatx4 acc[8][4];
    #pragma unroll
    for (int i = 0; i < 8; ++i)
        #pragma unroll
        for (int j = 0; j < 4; ++j)
            acc[i][j] = (floatx4)0.0f;

    // A staging: 256 rows x 64 k fp32 -> 8 float4/thread (8 passes of 32 rows;
    // per instr lanes cover 4 rows x 256 B runs -> coalesced).
    const int a_row = tid >> 4;          // 0..31
    const int a_kc  = (tid & 15) * 4;    // k-chunk 0..60
    // B staging: 64 k-rows x 256 n fp32 -> 8 float4/thread. Thread owns a
    // 4n x 4k micro-tile in each n-half (2 passes); per instr 2x512 B runs.
    const int b_i  = tid & 31;           // n-quad within half (n = 4*b_i + j)
    const int b_c8 = tid >> 5;           // k-quad index 0..15 (k = 4*b_c8 ..+3)

    const float* aBase = code + (size_t)l * C_ + a_kc;
    const float* wBase = W + (size_t)l * (C_ * HW_) + (size_t)(4 * b_c8) * HW_ + n0 + 4 * b_i;

    floatx4 Areg[8];      // depth-1 (depth-2 measured neutral in round 1)
    floatx4 Breg[2][4];   // [n-half][k-row]

    // ---- prologue: A(0), B(0) ----
    #pragma unroll
    for (int p = 0; p < 8; ++p)
        Areg[p] = *(const floatx4*)(aBase + (size_t)(p * 32 + a_row) * (L_ * C_));
    #pragma unroll
    for (int nh = 0; nh < 2; ++nh)
        #pragma unroll
        for (int r = 0; r < 4; ++r)
            Breg[nh][r] = *(const floatx4*)(wBase + (size_t)r * HW_ + nh * 128);

    #pragma unroll
    for (int kb = 0; kb < C_; kb += 64) {
        // ---- stage A: waits (in-order vmcnt) on A loads issued last iter ----
        #pragma unroll
        for (int p = 0; p < 8; ++p) {
            bf16x4 h;
            h.x = (__bf16)Areg[p].x; h.y = (__bf16)Areg[p].y;
            h.z = (__bf16)Areg[p].z; h.w = (__bf16)Areg[p].w;
            *(bf16x4*)&Alds[lds_addr(p * 32 + a_row, a_kc >> 3, (a_kc & 4) << 1)] = h;
        }
        // ---- stage B (register 4x4 transpose -> k-contiguous bf16x4) ----
        #pragma unroll
        for (int nh = 0; nh < 2; ++nh) {
            #pragma unroll
            for (int j = 0; j < 4; ++j) {
                bf16x4 h;
                h.x = (__bf16)Breg[nh][0][j]; h.y = (__bf16)Breg[nh][1][j];
                h.z = (__bf16)Breg[nh][2][j]; h.w = (__bf16)Breg[nh][3][j];
                const int row = 4 * (b_i + 32 * nh) + j;
                *(bf16x4*)&Blds[lds_addr(row, b_c8 >> 1, (b_c8 & 1) << 3)] = h;
            }
        }

        // ---- issue prefetch for kb+64 (in flight across both barriers) ----
        if (kb + 64 < C_) {
            #pragma unroll
            for (int p = 0; p < 8; ++p)
                Areg[p] = *(const floatx4*)(aBase + (size_t)(p * 32 + a_row) * (L_ * C_) + (kb + 64));
            #pragma unroll
            for (int nh = 0; nh < 2; ++nh)
                #pragma unroll
                for (int r = 0; r < 4; ++r)
                    Breg[nh][r] = *(const floatx4*)(wBase + (size_t)(kb + 64 + r) * HW_ + nh * 128);
        }

        BARRIER_LDS();   // LDS writes visible; vmcnt NOT drained

        // ---- compute: 2 k-steps of 32, 32 MFMA each ----
        #pragma unroll
        for (int ks = 0; ks < 2; ++ks) {
            bf16x8 af[8], bfr[4];
            const int koff = ks * 32 + (lane >> 4) * 8;
            const int c16  = koff >> 3;
            #pragma unroll
            for (int i = 0; i < 8; ++i)
                af[i] = *(const bf16x8*)&Alds[lds_addr(wm + i * 16 + (lane & 15), c16, 0)];
            #pragma unroll
            for (int j = 0; j < 4; ++j)
                bfr[j] = *(const bf16x8*)&Blds[lds_addr(wn + j * 16 + (lane & 15), c16, 0)];
            #pragma unroll
            for (int i = 0; i < 8; ++i)
                #pragma unroll
                for (int j = 0; j < 4; ++j)
                    acc[i][j] = __builtin_amdgcn_mfma_f32_16x16x32_bf16(af[i], bfr[j], acc[i][j], 0, 0, 0);
        }

        BARRIER_LDS();   // all waves done reading before next overwrite
    }

    // ---- epilogue: C/D layout col=lane&15, row=(lane>>4)*4+reg ----
    const int col0 = lane & 15;
    const int row0 = (lane >> 4) * 4;
    #pragma unroll
    for (int i = 0; i < 8; ++i) {
        #pragma unroll
        for (int j = 0; j < 4; ++j) {
            const int m = wm + i * 16 + row0;           // batch row (BM = whole batch)
            const int n = n0 + wn + j * 16 + col0;
            float* o = out + (size_t)m * (L_ * HW_) + (size_t)l * HW_ + n;
            #pragma unroll
            for (int r = 0; r < 4; ++r)
                o[(size_t)r * (L_ * HW_)] = acc[i][j][r];
        }
    }
}

extern "C" void kernel_launch(void* const* d_in, const int* in_sizes, int n_in,
                              void* d_out, int out_size, void* d_ws, size_t ws_size,
                              hipStream_t stream) {
    const float* code = (const float*)d_in[0];   // [256, 64, 256] fp32
    const float* W    = (const float*)d_in[1];   // [64, 256, 1024] fp32
    float* out        = (float*)d_out;           // [256, 64, 32, 32] fp32

    gld_mfma_kernel<<<dim3(256), 512, 0, stream>>>(code, W, out);
}